// Round 3
// baseline (236.098 us; speedup 1.0000x reference)
//
#include <hip/hip_runtime.h>
#include <hip/hip_bf16.h>

// CARAFE-style SAU. Round 3: conv re-tile (32px x 64co blocks, balanced ds/MFMA),
// reassembly occupancy fix (no ker LDS stage, 7 blocks/CU).
// N=8, Cin=128, H=W=64, Cmid=64, NK=100, K=5, S=2.

typedef __attribute__((ext_vector_type(8))) short short8;
typedef __attribute__((ext_vector_type(4))) float f32x4;

// ---------------- prep: x (N,128,64,64) f32 -> xb (N,64,64,128) bf16 ----------------
__global__ __launch_bounds__(256) void x_to_bf_nhwc(const float* __restrict__ x,
                                                    __hip_bfloat16* __restrict__ xb) {
    __shared__ float ls[128 * 65];
    const int blk = blockIdx.x, n = blk >> 6, h = blk & 63;
    const int tid = threadIdx.x;
    for (int idx = tid; idx < 8192; idx += 256) {
        int ci = idx >> 6, w = idx & 63;
        ls[ci * 65 + w] = x[((n * 128 + ci) * 64 + h) * 64 + w];
    }
    __syncthreads();
    for (int idx = tid; idx < 8192; idx += 256) {
        int w = idx >> 7, ci = idx & 127;
        xb[((n * 64 + h) * 64 + w) * 128 + ci] = __float2bfloat16(ls[ci * 65 + w]);
    }
}

// ---------------- prep: weights (64,CI,3,3) f32 -> (3,3,64,CI) bf16 ----------------
__global__ void w_to_bf(const float* __restrict__ w, __hip_bfloat16* __restrict__ o,
                        int CI, int total) {
    int idx = blockIdx.x * 256 + threadIdx.x;
    if (idx >= total) return;
    int ci = idx % CI;
    int t = idx / CI;
    int co = t & 63;
    int p = t >> 6;  // kh*3+kw
    o[idx] = __float2bfloat16(w[(co * CI + ci) * 9 + p]);
}

// ---------------- conv3x3 via MFMA 16x16x32 bf16 ----------------
// xb: (N,64,64,CIN) bf16 NHWC; wt: (3,3,64,CIN) bf16.
// Block per (n, h, w-half): 32 px x 64 co. Wave = one 16-px m-tile x 32 co (2 n-tiles).
// Per k-step: 1 ds_read_b128 (A) + 2 global b128 (B) + 2 MFMA.
template<int CIN>
__global__ __launch_bounds__(256) void conv3x3_mfma(
    const __hip_bfloat16* __restrict__ xb, const __hip_bfloat16* __restrict__ wt,
    const float* __restrict__ bias, const float* __restrict__ gamma,
    const float* __restrict__ beta, const float* __restrict__ mean,
    const float* __restrict__ var,
    float* __restrict__ out_f32,          // (N,64,64,64) NHWC f32, may be null
    __hip_bfloat16* __restrict__ out_bf)  // (N,64,64,64) NHWC bf16, may be null
{
    constexpr int CINP = CIN + 4;  // +4 shorts (8B) pad -> spread LDS banks
    __shared__ short xs[3 * 34 * CINP];  // rows h-1..h+1, cols wh*32-1 .. wh*32+32
    const int blk = blockIdx.x;
    const int wh = blk & 1, h = (blk >> 1) & 63, n = blk >> 7;
    const int tid = threadIdx.x;
    const int lane = tid & 63, wave = tid >> 6;
    const int m = lane & 15, q = lane >> 4;
    const int mt = wave >> 1;       // which 16-px tile of the 32
    const int nh = wave & 1;        // which 32-co half

    // stage x: 3 rows x 34 cols x CIN, ci-contiguous 16B chunks, zero pad OOB
    const short8 zero8 = {0, 0, 0, 0, 0, 0, 0, 0};
    for (int idx = tid; idx < 3 * 34 * (CIN / 8); idx += 256) {
        int c8 = idx % (CIN / 8);
        int p = idx / (CIN / 8);
        int r = p / 34, cx = p % 34;
        int hh = h + r - 1, gc = wh * 32 - 1 + cx;
        short8 v = zero8;
        if ((unsigned)hh < 64u && (unsigned)gc < 64u)
            v = *(const short8*)&xb[(((n * 64 + hh) * 64 + gc) * CIN) + c8 * 8];
        *(short8*)&xs[(r * 34 + cx) * CINP + c8 * 8] = v;
    }
    __syncthreads();

    f32x4 acc[2] = {{0.f, 0.f, 0.f, 0.f}, {0.f, 0.f, 0.f, 0.f}};
    const int kbase = q * 8;
    #pragma unroll
    for (int kh = 0; kh < 3; ++kh) {
        #pragma unroll
        for (int kw = 0; kw < 3; ++kw) {
            // A frag: pixel-in-block pb = mt*16+m, xs col = pb + kw
            const short* xp = &xs[(kh * 34 + mt * 16 + m + kw) * CINP + kbase];
            const __hip_bfloat16* wp = &wt[((kh * 3 + kw) * 64 + nh * 32 + m) * CIN + kbase];
            #pragma unroll
            for (int kc = 0; kc < CIN / 32; ++kc) {
                short8 afrag = *(const short8*)&xp[kc * 32];
                short8 b0 = *(const short8*)&wp[kc * 32];
                short8 b1 = *(const short8*)&wp[16 * CIN + kc * 32];
                acc[0] = __builtin_amdgcn_mfma_f32_16x16x32_bf16(afrag, b0, acc[0], 0, 0, 0);
                acc[1] = __builtin_amdgcn_mfma_f32_16x16x32_bf16(afrag, b1, acc[1], 0, 0, 0);
            }
        }
    }

    // epilogue: C/D layout col(m)=cout-in-tile, row(q*4+r)=pixel-in-tile
    #pragma unroll
    for (int nt = 0; nt < 2; ++nt) {
        const int c = nh * 32 + nt * 16 + m;
        float sc, sh;
        if (gamma) {
            float inv = rsqrtf(var[c] + 1e-5f);
            sc = gamma[c] * inv;
            sh = (bias[c] - mean[c]) * sc + beta[c];
        } else {
            sc = 1.f;
            sh = bias[c];
        }
        const int w0 = wh * 32 + mt * 16 + q * 4;
        #pragma unroll
        for (int r = 0; r < 4; ++r) {
            float ov = fmaxf(fmaf(acc[nt][r], sc, sh), 0.f);
            const int gi = ((n * 64 + h) * 64 + (w0 + r)) * 64 + c;
            if (out_f32) out_f32[gi] = ov;
            if (out_bf)  out_bf[gi] = __float2bfloat16(ov);
        }
    }
}

// ---------------- fused kernel/gate predictor + softmax ----------------
__global__ __launch_bounds__(256) void predictor_k(
    const __hip_bfloat16* __restrict__ cb, const float* __restrict__ g1,
    const float* __restrict__ wkp, const float* __restrict__ bkp,
    const float* __restrict__ wg2, const float* __restrict__ bg2,
    float* __restrict__ ker)
{
    __shared__ float cs[64 * 68];
    __shared__ float gs[64 * 68];
    __shared__ float wsm[100 * 64];
    __shared__ float redm[256], reds[256];
    const int blk = blockIdx.x;
    const int n = blk >> 6, h = blk & 63;
    const int tid = threadIdx.x;
    const int w = tid & 63, qg = tid >> 6;

    for (int idx = tid; idx < 4096; idx += 256) {
        int ww = idx >> 6, ci = idx & 63;
        const int gidx = ((n * 64 + h) * 64 + ww) * 64 + ci;
        cs[ww * 68 + ci] = __bfloat162float(cb[gidx]);
        gs[ww * 68 + ci] = g1[gidx];
    }
    for (int idx = tid; idx < 6400; idx += 256) wsm[idx] = wkp[idx];
    __syncthreads();

    float ka[25], ga[25];
    #pragma unroll
    for (int j = 0; j < 25; ++j) ka[j] = bkp[qg * 25 + j];
    for (int ci = 0; ci < 64; ci += 4) {
        const float4 cv = *(const float4*)&cs[w * 68 + ci];
        #pragma unroll
        for (int j = 0; j < 25; ++j) {
            const float4 wv = *(const float4*)&wsm[(qg * 25 + j) * 64 + ci];
            ka[j] = fmaf(cv.x, wv.x, ka[j]);
            ka[j] = fmaf(cv.y, wv.y, ka[j]);
            ka[j] = fmaf(cv.z, wv.z, ka[j]);
            ka[j] = fmaf(cv.w, wv.w, ka[j]);
        }
    }
    __syncthreads();
    for (int idx = tid; idx < 6400; idx += 256) wsm[idx] = wg2[idx];
    __syncthreads();
    #pragma unroll
    for (int j = 0; j < 25; ++j) ga[j] = bg2[qg * 25 + j];
    for (int ci = 0; ci < 64; ci += 4) {
        const float4 gv = *(const float4*)&gs[w * 68 + ci];
        #pragma unroll
        for (int j = 0; j < 25; ++j) {
            const float4 wv = *(const float4*)&wsm[(qg * 25 + j) * 64 + ci];
            ga[j] = fmaf(gv.x, wv.x, ga[j]);
            ga[j] = fmaf(gv.y, wv.y, ga[j]);
            ga[j] = fmaf(gv.z, wv.z, ga[j]);
            ga[j] = fmaf(gv.w, wv.w, ga[j]);
        }
    }

    float p[25], m = -1e30f;
    #pragma unroll
    for (int j = 0; j < 25; ++j) {
        float s = 1.f / (1.f + __expf(-ga[j]));
        p[j] = ka[j] * s;
        m = fmaxf(m, p[j]);
    }
    redm[tid] = m;
    __syncthreads();
    m = fmaxf(fmaxf(redm[w], redm[64 + w]), fmaxf(redm[128 + w], redm[192 + w]));
    float ssum = 0.f;
    #pragma unroll
    for (int j = 0; j < 25; ++j) { p[j] = __expf(p[j] - m); ssum += p[j]; }
    reds[tid] = ssum;
    __syncthreads();
    ssum = reds[w] + reds[64 + w] + reds[128 + w] + reds[192 + w];
    const float r = 1.f / ssum;

    float* sm = cs;  // reuse cs+gs region (contiguous, 8704 floats >= 6400)
    #pragma unroll
    for (int j = 0; j < 25; ++j) sm[w * 100 + qg * 25 + j] = p[j] * r;
    __syncthreads();
    const int base = (n * 64 + h) * 6400;
    for (int idx = tid; idx < 6400; idx += 256) ker[base + idx] = sm[idx];
}

// ---------------- content-aware reassembly + pixel shuffle ----------------
// x: (N,128,64,64) f32, ker: (N,H,W,100) f32, out: (N,128,128,128).
// Block = (n, h, 16-ch chunk); LDS only stages x (21.8 KB -> 7 blocks/CU).
// ker read per-thread direct from global (400 B/thread contiguous, L1/L2-served).
__global__ __launch_bounds__(256) void reassembly_k(
    const float* __restrict__ x, const float* __restrict__ ker,
    float* __restrict__ out)
{
    constexpr int CT = 16;
    __shared__ float xls[CT][5][68];   // [c][row][col_mem], col_mem = x_col + 2 (replicate pad)
    const int blk = blockIdx.x;
    const int cb = blk & 7, h = (blk >> 3) & 63, n = blk >> 9;
    const int c0 = cb * CT;
    const int tid = threadIdx.x;
    const int w = tid & 63, cg = tid >> 6;

    // interior: 16ch x 5 rows x 16 float4 (cols 0..63 -> col_mem 2..65)
    for (int idx = tid; idx < CT * 5 * 16; idx += 256) {
        int c = idx / 80, r2 = idx % 80;
        int rr = r2 / 16, c4 = r2 % 16;
        int sr = min(max(h - 2 + rr, 0), 63);
        float4 v = *(const float4*)&x[((n * 128 + c0 + c) * 64 + sr) * 64 + c4 * 4];
        *(float2*)&xls[c][rr][2 + c4 * 4] = make_float2(v.x, v.y);
        *(float2*)&xls[c][rr][4 + c4 * 4] = make_float2(v.z, v.w);
    }
    // halo: replicate cols 0 and 63
    if (tid < CT * 5) {
        int c = tid / 5, rr = tid % 5;
        int sr = min(max(h - 2 + rr, 0), 63);
        float xl = x[((n * 128 + c0 + c) * 64 + sr) * 64 + 0];
        float xr = x[((n * 128 + c0 + c) * 64 + sr) * 64 + 63];
        xls[c][rr][0] = xl; xls[c][rr][1] = xl;
        xls[c][rr][66] = xr; xls[c][rr][67] = xr;
    }
    __syncthreads();

    const float* kp = &ker[((n * 64 + h) * 64 + w) * 100];
    float acc[4][4] = {};
    #pragma unroll
    for (int i = 0; i < 5; ++i) {
        #pragma unroll
        for (int j = 0; j < 5; ++j) {
            const float4 kv = *(const float4*)&kp[(i * 5 + j) * 4];
            #pragma unroll
            for (int cc = 0; cc < 4; ++cc) {
                const float xv = xls[cg * 4 + cc][i][w + j];
                acc[cc][0] = fmaf(xv, kv.x, acc[cc][0]);
                acc[cc][1] = fmaf(xv, kv.y, acc[cc][1]);
                acc[cc][2] = fmaf(xv, kv.z, acc[cc][2]);
                acc[cc][3] = fmaf(xv, kv.w, acc[cc][3]);
            }
        }
    }
    #pragma unroll
    for (int cc = 0; cc < 4; ++cc) {
        const int c = c0 + cg * 4 + cc;
        #pragma unroll
        for (int s = 0; s < 2; ++s) {
            float2 v = make_float2(acc[cc][s * 2], acc[cc][s * 2 + 1]);
            *(float2*)&out[((n * 128 + c) * 128 + 2 * h + s) * 128 + 2 * w] = v;
        }
    }
}

extern "C" void kernel_launch(void* const* d_in, const int* in_sizes, int n_in,
                              void* d_out, int out_size, void* d_ws, size_t ws_size,
                              hipStream_t stream) {
    const float* x     = (const float*)d_in[0];
    const float* w_enc = (const float*)d_in[1];
    const float* b_enc = (const float*)d_in[2];
    const float* gamma = (const float*)d_in[3];
    const float* beta  = (const float*)d_in[4];
    const float* mean  = (const float*)d_in[5];
    const float* var   = (const float*)d_in[6];
    const float* w_kp  = (const float*)d_in[7];
    const float* b_kp  = (const float*)d_in[8];
    const float* w_g1  = (const float*)d_in[9];
    const float* b_g1  = (const float*)d_in[10];
    const float* w_g2  = (const float*)d_in[11];
    const float* b_g2  = (const float*)d_in[12];
    float* out = (float*)d_out;

    // workspace carve
    float* g1r = (float*)d_ws;                     // (N,64,64,64) NHWC f32
    float* ker = g1r + 2097152;                    // (N,H,W,100)  f32
    __hip_bfloat16* xb  = (__hip_bfloat16*)(ker + 3276800);  // (N,64,64,128) bf16
    __hip_bfloat16* cbf = xb + 4194304;            // content (N,64,64,64) bf16
    __hip_bfloat16* wtt = cbf + 2097152;           // (3,3,64,128) bf16
    __hip_bfloat16* wgt = wtt + 73728;             // (3,3,64,64) bf16

    x_to_bf_nhwc<<<512, 256, 0, stream>>>(x, xb);
    w_to_bf<<<288, 256, 0, stream>>>(w_enc, wtt, 128, 73728);
    w_to_bf<<<144, 256, 0, stream>>>(w_g1, wgt, 64, 36864);

    conv3x3_mfma<128><<<1024, 256, 0, stream>>>(
        xb, wtt, b_enc, gamma, beta, mean, var, nullptr, cbf);
    conv3x3_mfma<64><<<1024, 256, 0, stream>>>(
        cbf, wgt, b_g1, nullptr, nullptr, nullptr, nullptr, g1r, nullptr);

    predictor_k<<<512, 256, 0, stream>>>(cbf, g1r, w_kp, b_kp, w_g2, b_g2, ker);
    reassembly_k<<<4096, 256, 0, stream>>>(x, ker, out);
}

// Round 4
// 226.354 us; speedup vs baseline: 1.0430x; 1.0430x over previous
//
#include <hip/hip_runtime.h>
#include <hip/hip_bf16.h>

// CARAFE-style SAU. Round 4:
//  - convs: LDS-free direct MFMA on zero-padded NHWC bf16 input (no barriers)
//  - predictor: MFMA GEMMs (64px x 112co x K64) + fused softmax, ker stored PLANAR
//  - reassembly: planar ker -> lane-coalesced scalar loads (kills line-request bound)
// N=8, Cin=128, H=W=64, Cmid=64, NK=100, K=5, S=2.

typedef __attribute__((ext_vector_type(8))) short short8;
typedef __attribute__((ext_vector_type(4))) float f32x4;

// ---------------- zero fill (for padded buffers' borders) ----------------
__global__ void zerofill8(short* __restrict__ p, int n8) {
    int i = blockIdx.x * 256 + threadIdx.x;
    if (i < n8) ((short8*)p)[i] = (short8){0, 0, 0, 0, 0, 0, 0, 0};
}

// ---------------- prep: x (N,128,64,64) f32 -> xb (N,66,66,128) bf16 zero-padded ----------------
__global__ __launch_bounds__(256) void x_to_bf_pad(const float* __restrict__ x,
                                                   __hip_bfloat16* __restrict__ xb) {
    __shared__ float ls[128 * 65];
    const int blk = blockIdx.x, n = blk >> 6, h = blk & 63;
    const int tid = threadIdx.x;
    for (int idx = tid; idx < 8192; idx += 256) {
        int ci = idx >> 6, w = idx & 63;
        ls[ci * 65 + w] = x[((n * 128 + ci) * 64 + h) * 64 + w];
    }
    __syncthreads();
    for (int idx = tid; idx < 8192; idx += 256) {
        int w = idx >> 7, ci = idx & 127;
        xb[(((n * 66 + h + 1) * 66) + w + 1) * 128 + ci] = __float2bfloat16(ls[ci * 65 + w]);
    }
}

// ---------------- prep: conv weights (64,CI,3,3) f32 -> (3,3,64,CI) bf16 ----------------
__global__ void w_to_bf(const float* __restrict__ w, __hip_bfloat16* __restrict__ o,
                        int CI, int total) {
    int idx = blockIdx.x * 256 + threadIdx.x;
    if (idx >= total) return;
    int ci = idx % CI;
    int t = idx / CI;
    int co = t & 63;
    int p = t >> 6;  // kh*3+kw
    o[idx] = __float2bfloat16(w[(co * CI + ci) * 9 + p]);
}

// ---------------- prep: predictor weights (100,64) f32 -> [112][64] bf16 zero-padded ----------------
__global__ void wpred_to_bf(const float* __restrict__ wkp, const float* __restrict__ wg2,
                            __hip_bfloat16* __restrict__ kt, __hip_bfloat16* __restrict__ gt) {
    int idx = blockIdx.x * 256 + threadIdx.x;
    if (idx >= 7168) return;
    int co = idx >> 6, ci = idx & 63;
    float a = co < 100 ? wkp[co * 64 + ci] : 0.f;
    float b = co < 100 ? wg2[co * 64 + ci] : 0.f;
    kt[idx] = __float2bfloat16(a);
    gt[idx] = __float2bfloat16(b);
}

// ---------------- conv3x3: LDS-free direct MFMA ----------------
// xp: (N,66,66,CIN) bf16 zero-padded; wt: (3,3,64,CIN) bf16.
// Block = (n, h, w-half): 32 px x 64 co. 4 waves: (px-16-half, co-32-half).
// Wave: 1 m-tile (16px) x 2 n-tiles (32co). Per k-step: 1 A + 2 B global b128 + 2 MFMA.
template<int CIN, bool PADOUT, bool BN>
__global__ __launch_bounds__(256) void conv3x3_direct(
    const __hip_bfloat16* __restrict__ xp, const __hip_bfloat16* __restrict__ wt,
    const float* __restrict__ bias, const float* __restrict__ gamma,
    const float* __restrict__ beta, const float* __restrict__ mean,
    const float* __restrict__ var,
    __hip_bfloat16* __restrict__ outp)
{
    const int blk = blockIdx.x;
    const int wseg = blk & 1, h = (blk >> 1) & 63, n = blk >> 7;
    const int tid = threadIdx.x;
    const int lane = tid & 63, wave = tid >> 6;
    const int m = lane & 15, q = lane >> 4;
    const int nh = wave & 1, ph = wave >> 1;
    const int px = wseg * 32 + ph * 16 + m;   // A-row pixel for this lane
    const int cob = nh * 32;
    const int krow = q * 8;

    f32x4 acc[2] = {{0.f, 0.f, 0.f, 0.f}, {0.f, 0.f, 0.f, 0.f}};
    const short* arow = (const short*)xp + (((n * 66 + h) * 66) + px) * CIN + krow;
    const short* wbase = (const short*)wt + (cob + m) * CIN + krow;

    #pragma unroll
    for (int kh = 0; kh < 3; ++kh) {
        #pragma unroll
        for (int kw = 0; kw < 3; ++kw) {
            const short* ap = arow + (kh * 66 + kw) * CIN;
            const short* bp = wbase + (kh * 3 + kw) * 64 * CIN;
            #pragma unroll
            for (int kc = 0; kc < CIN / 32; ++kc) {
                short8 af = *(const short8*)(ap + kc * 32);
                short8 b0 = *(const short8*)(bp + kc * 32);
                short8 b1 = *(const short8*)(bp + 16 * CIN + kc * 32);
                acc[0] = __builtin_amdgcn_mfma_f32_16x16x32_bf16(af, b0, acc[0], 0, 0, 0);
                acc[1] = __builtin_amdgcn_mfma_f32_16x16x32_bf16(af, b1, acc[1], 0, 0, 0);
            }
        }
    }

    // epilogue: C/D col(m)=co-in-tile, row(q*4+r)=px-in-tile
    #pragma unroll
    for (int nt = 0; nt < 2; ++nt) {
        const int c = cob + nt * 16 + m;
        float sc, sh;
        if constexpr (BN) {
            float inv = rsqrtf(var[c] + 1e-5f);
            sc = gamma[c] * inv;
            sh = (bias[c] - mean[c]) * sc + beta[c];
        } else {
            sc = 1.f;
            sh = bias[c];
        }
        #pragma unroll
        for (int r = 0; r < 4; ++r) {
            const int pxr = wseg * 32 + ph * 16 + q * 4 + r;
            float ov = fmaxf(fmaf(acc[nt][r], sc, sh), 0.f);
            if constexpr (PADOUT)
                outp[(((n * 66 + h + 1) * 66) + pxr + 1) * 64 + c] = __float2bfloat16(ov);
            else
                outp[((n * 64 + h) * 64 + pxr) * 64 + c] = __float2bfloat16(ov);
        }
    }
}

// ---------------- predictor: 2 MFMA GEMMs (64px x 112 x K64) + sigmoid-gate softmax ----------------
// cbf: padded content bf16 (N,66,66,64); g1bf: (N,64,64,64) bf16.
// wkpt/wg2t: [112][64] bf16. ker out: PLANAR (N,100,64,64) f32.
__global__ __launch_bounds__(256) void predictor_mfma(
    const __hip_bfloat16* __restrict__ cbf, const __hip_bfloat16* __restrict__ g1bf,
    const __hip_bfloat16* __restrict__ wkpt, const __hip_bfloat16* __restrict__ wg2t,
    const float* __restrict__ bkp, const float* __restrict__ bg2,
    float* __restrict__ ker)
{
    __shared__ float kers[64 * 117];
    __shared__ float gates[64 * 117];
    __shared__ float redm[256], reds[256];
    const int blk = blockIdx.x, n = blk >> 6, h = blk & 63;
    const int tid = threadIdx.x;
    const int lane = tid & 63, wave = tid >> 6;
    const int m = lane & 15, q = lane >> 4;
    const int sel = wave >> 1;          // 0: kernel-pred, 1: gate
    const int half = wave & 1;          // 0: n-tiles 0-3, 1: n-tiles 4-6
    const int nt0 = half ? 4 : 0, ntc = half ? 3 : 4;

    const short* A = sel ? (const short*)g1bf + ((n * 64 + h) * 64) * 64
                         : (const short*)cbf + (((n * 66 + h + 1) * 66) + 1) * 64;
    const short* B = sel ? (const short*)wg2t : (const short*)wkpt;

    f32x4 acc[4][4];
    #pragma unroll
    for (int a = 0; a < 4; ++a)
        #pragma unroll
        for (int b = 0; b < 4; ++b) acc[a][b] = (f32x4){0.f, 0.f, 0.f, 0.f};

    #pragma unroll
    for (int ks = 0; ks < 2; ++ks) {
        short8 af[4];
        #pragma unroll
        for (int mt = 0; mt < 4; ++mt)
            af[mt] = *(const short8*)(A + (mt * 16 + m) * 64 + ks * 32 + q * 8);
        #pragma unroll
        for (int nt = 0; nt < 4; ++nt) {
            if (nt >= ntc) break;
            short8 bf8 = *(const short8*)(B + ((nt0 + nt) * 16 + m) * 64 + ks * 32 + q * 8);
            #pragma unroll
            for (int mt = 0; mt < 4; ++mt)
                acc[mt][nt] = __builtin_amdgcn_mfma_f32_16x16x32_bf16(af[mt], bf8, acc[mt][nt], 0, 0, 0);
        }
    }

    float* dst = sel ? gates : kers;
    #pragma unroll
    for (int mt = 0; mt < 4; ++mt) {
        #pragma unroll
        for (int nt = 0; nt < 4; ++nt) {
            if (nt >= ntc) break;
            const int co = (nt0 + nt) * 16 + m;
            if (co < 100) {
                #pragma unroll
                for (int r = 0; r < 4; ++r)
                    dst[(mt * 16 + q * 4 + r) * 117 + co] = acc[mt][nt][r];
            }
        }
    }
    __syncthreads();

    // softmax over 100: thread = (w, qg), qg owns 25 q
    const int w = tid & 63, qg = tid >> 6;
    float p[25], mx = -1e30f;
    #pragma unroll
    for (int j = 0; j < 25; ++j) {
        const int qq = qg * 25 + j;
        float ka = kers[w * 117 + qq] + bkp[qq];
        float ga = gates[w * 117 + qq] + bg2[qq];
        p[j] = ka * (1.f / (1.f + __expf(-ga)));
        mx = fmaxf(mx, p[j]);
    }
    redm[tid] = mx;
    __syncthreads();
    mx = fmaxf(fmaxf(redm[w], redm[64 + w]), fmaxf(redm[128 + w], redm[192 + w]));
    float ssum = 0.f;
    #pragma unroll
    for (int j = 0; j < 25; ++j) { p[j] = __expf(p[j] - mx); ssum += p[j]; }
    reds[tid] = ssum;
    __syncthreads();
    ssum = reds[w] + reds[64 + w] + reds[128 + w] + reds[192 + w];
    const float r = 1.f / ssum;

    // planar store: ker[n][q][h][w] — lane-consecutive w, coalesced
    #pragma unroll
    for (int j = 0; j < 25; ++j) {
        const int qq = qg * 25 + j;
        ker[((n * 100 + qq) * 64 + h) * 64 + w] = p[j] * r;
    }
}

// ---------------- content-aware reassembly + pixel shuffle ----------------
// x: (N,128,64,64) f32, ker: PLANAR (N,100,64,64) f32, out: (N,128,128,128).
// Block = (n, h, 16-ch chunk). ker reads: lane-consecutive scalars (coalesced).
__global__ __launch_bounds__(256) void reassembly_k(
    const float* __restrict__ x, const float* __restrict__ ker,
    float* __restrict__ out)
{
    constexpr int CT = 16;
    __shared__ float xls[CT][5][68];   // [c][row][col_mem], col_mem = x_col + 2 (replicate pad)
    const int blk = blockIdx.x;
    const int cb = blk & 7, h = (blk >> 3) & 63, n = blk >> 9;
    const int c0 = cb * CT;
    const int tid = threadIdx.x;
    const int w = tid & 63, cg = tid >> 6;

    for (int idx = tid; idx < CT * 5 * 16; idx += 256) {
        int c = idx / 80, r2 = idx % 80;
        int rr = r2 / 16, c4 = r2 % 16;
        int sr = min(max(h - 2 + rr, 0), 63);
        float4 v = *(const float4*)&x[((n * 128 + c0 + c) * 64 + sr) * 64 + c4 * 4];
        *(float2*)&xls[c][rr][2 + c4 * 4] = make_float2(v.x, v.y);
        *(float2*)&xls[c][rr][4 + c4 * 4] = make_float2(v.z, v.w);
    }
    if (tid < CT * 5) {
        int c = tid / 5, rr = tid % 5;
        int sr = min(max(h - 2 + rr, 0), 63);
        float xl = x[((n * 128 + c0 + c) * 64 + sr) * 64 + 0];
        float xr = x[((n * 128 + c0 + c) * 64 + sr) * 64 + 63];
        xls[c][rr][0] = xl; xls[c][rr][1] = xl;
        xls[c][rr][66] = xr; xls[c][rr][67] = xr;
    }
    __syncthreads();

    const float* kbase = &ker[(n * 100 * 4096) + h * 64 + w];  // + q*4096
    float4 acc[4] = {{0.f, 0.f, 0.f, 0.f}, {0.f, 0.f, 0.f, 0.f},
                     {0.f, 0.f, 0.f, 0.f}, {0.f, 0.f, 0.f, 0.f}};
    #pragma unroll
    for (int i = 0; i < 5; ++i) {
        #pragma unroll
        for (int j = 0; j < 5; ++j) {
            const int q0 = (i * 5 + j) * 4;
            const float k0 = kbase[(q0 + 0) * 4096];
            const float k1 = kbase[(q0 + 1) * 4096];
            const float k2 = kbase[(q0 + 2) * 4096];
            const float k3 = kbase[(q0 + 3) * 4096];
            #pragma unroll
            for (int cc = 0; cc < 4; ++cc) {
                const float xv = xls[cg * 4 + cc][i][w + j];
                acc[cc].x = fmaf(xv, k0, acc[cc].x);
                acc[cc].y = fmaf(xv, k1, acc[cc].y);
                acc[cc].z = fmaf(xv, k2, acc[cc].z);
                acc[cc].w = fmaf(xv, k3, acc[cc].w);
            }
        }
    }
    #pragma unroll
    for (int cc = 0; cc < 4; ++cc) {
        const int c = c0 + cg * 4 + cc;
        *(float2*)&out[((n * 128 + c) * 128 + 2 * h + 0) * 128 + 2 * w] =
            make_float2(acc[cc].x, acc[cc].y);
        *(float2*)&out[((n * 128 + c) * 128 + 2 * h + 1) * 128 + 2 * w] =
            make_float2(acc[cc].z, acc[cc].w);
    }
}

extern "C" void kernel_launch(void* const* d_in, const int* in_sizes, int n_in,
                              void* d_out, int out_size, void* d_ws, size_t ws_size,
                              hipStream_t stream) {
    const float* x     = (const float*)d_in[0];
    const float* w_enc = (const float*)d_in[1];
    const float* b_enc = (const float*)d_in[2];
    const float* gamma = (const float*)d_in[3];
    const float* beta  = (const float*)d_in[4];
    const float* mean  = (const float*)d_in[5];
    const float* var   = (const float*)d_in[6];
    const float* w_kp  = (const float*)d_in[7];
    const float* b_kp  = (const float*)d_in[8];
    const float* w_g1  = (const float*)d_in[9];
    const float* b_g1  = (const float*)d_in[10];
    const float* w_g2  = (const float*)d_in[11];
    const float* b_g2  = (const float*)d_in[12];
    float* out = (float*)d_out;

    // ws carve (bytes all 16B-aligned)
    float* ker = (float*)d_ws;                               // (N,100,64,64) f32
    __hip_bfloat16* g1bf = (__hip_bfloat16*)(ker + 3276800); // (N,64,64,64) bf16
    __hip_bfloat16* xb   = g1bf + 2097152;                   // (N,66,66,128) bf16
    __hip_bfloat16* cbf  = xb + 4460544;                     // (N,66,66,64) bf16
    __hip_bfloat16* wtt  = cbf + 2230272;                    // (3,3,64,128) bf16
    __hip_bfloat16* wgt  = wtt + 73728;                      // (3,3,64,64) bf16
    __hip_bfloat16* wkpt = wgt + 36864;                      // [112][64] bf16
    __hip_bfloat16* wg2t = wkpt + 7168;                      // [112][64] bf16

    // zero xb+cbf (contiguous, 6,690,816 shorts = 836,352 short8)
    zerofill8<<<3267, 256, 0, stream>>>((short*)xb, 836352);
    x_to_bf_pad<<<512, 256, 0, stream>>>(x, xb);
    w_to_bf<<<288, 256, 0, stream>>>(w_enc, wtt, 128, 73728);
    w_to_bf<<<144, 256, 0, stream>>>(w_g1, wgt, 64, 36864);
    wpred_to_bf<<<28, 256, 0, stream>>>(w_kp, w_g2, wkpt, wg2t);

    conv3x3_direct<128, true, true><<<1024, 256, 0, stream>>>(
        xb, wtt, b_enc, gamma, beta, mean, var, cbf);
    conv3x3_direct<64, false, false><<<1024, 256, 0, stream>>>(
        cbf, wgt, b_g1, nullptr, nullptr, nullptr, nullptr, g1bf);

    predictor_mfma<<<512, 256, 0, stream>>>(cbf, g1bf, wkpt, wg2t, b_kp, b_g2, ker);
    reassembly_k<<<4096, 256, 0, stream>>>(x, ker, out);
}

// Round 5
// 186.570 us; speedup vs baseline: 1.2655x; 1.2132x over previous
//
#include <hip/hip_runtime.h>
#include <hip/hip_bf16.h>

// CARAFE-style SAU. Round 5:
//  - convs: single-barrier LDS-staged MFMA. Full 3-row halo staged once (div-free,
//    coalesced, +4-short pixel pad -> ~4-way max bank aliasing). Weights pre-shuffled
//    to exact MFMA B-frag lane order -> 1KB coalesced global loads (L2-resident).
//    Wave = 2 m-tiles x 2 n-tiles: LDS/L1/MFMA pipes balanced.
//  - predictor: MFMA GEMMs + fused softmax, ker stored planar (N,100,H,W)
//  - reassembly: planar ker, lane-coalesced scalar loads
// N=8, Cin=128, H=W=64, Cmid=64, NK=100, K=5, S=2.

typedef __attribute__((ext_vector_type(8))) short short8;
typedef __attribute__((ext_vector_type(4))) float f32x4;

// ---------------- zero fill (for padded buffers' borders) ----------------
__global__ void zerofill8(short* __restrict__ p, int n8) {
    int i = blockIdx.x * 256 + threadIdx.x;
    if (i < n8) ((short8*)p)[i] = (short8){0, 0, 0, 0, 0, 0, 0, 0};
}

// ---------------- prep: x (N,128,64,64) f32 -> xb (N,66,66,128) bf16 zero-padded ----------------
__global__ __launch_bounds__(256) void x_to_bf_pad(const float* __restrict__ x,
                                                   __hip_bfloat16* __restrict__ xb) {
    __shared__ float ls[128 * 65];
    const int blk = blockIdx.x, n = blk >> 6, h = blk & 63;
    const int tid = threadIdx.x;
    for (int idx = tid; idx < 8192; idx += 256) {
        int ci = idx >> 6, w = idx & 63;
        ls[ci * 65 + w] = x[((n * 128 + ci) * 64 + h) * 64 + w];
    }
    __syncthreads();
    for (int idx = tid; idx < 8192; idx += 256) {
        int w = idx >> 7, ci = idx & 127;
        xb[(((n * 66 + h + 1) * 66) + w + 1) * 128 + ci] = __float2bfloat16(ls[ci * 65 + w]);
    }
}

// ---------------- prep: conv weights (64,CI,3,3) -> MFMA B-frag layout ----------------
// o[((tap*KC + kc)*4 + nt)*512 + lane*8 + j] = w(co = nt*16 + (lane&15),
//                                               ci = kc*32 + (lane>>4)*8 + j, tap)
template<int KC>
__global__ void w_frag(const float* __restrict__ w, __hip_bfloat16* __restrict__ o,
                       int total) {
    constexpr int CIN = KC * 32;
    int idx = blockIdx.x * 256 + threadIdx.x;
    if (idx >= total) return;
    int j = idx & 7;
    int lane = (idx >> 3) & 63;
    int nt = (idx >> 9) & 3;
    int kc = (idx >> 11) & (KC - 1);
    int tap = idx >> (KC == 4 ? 13 : 12);
    int co = nt * 16 + (lane & 15);
    int ci = kc * 32 + (lane >> 4) * 8 + j;
    o[idx] = __float2bfloat16(w[(co * CIN + ci) * 9 + tap]);
}

// ---------------- prep: predictor weights (100,64) f32 -> [112][64] bf16 zero-padded ----------------
__global__ void wpred_to_bf(const float* __restrict__ wkp, const float* __restrict__ wg2,
                            __hip_bfloat16* __restrict__ kt, __hip_bfloat16* __restrict__ gt) {
    int idx = blockIdx.x * 256 + threadIdx.x;
    if (idx >= 7168) return;
    int co = idx >> 6, ci = idx & 63;
    float a = co < 100 ? wkp[co * 64 + ci] : 0.f;
    float b = co < 100 ? wg2[co * 64 + ci] : 0.f;
    kt[idx] = __float2bfloat16(a);
    gt[idx] = __float2bfloat16(b);
}

// ---------------- conv3x3: single-barrier LDS-staged MFMA ----------------
// xp: (N,66,66,CIN) bf16 zero-padded; wb: B-frag layout (see w_frag).
// Block = 1 output row: 64 px x 64 co. Grid 512. 4 waves: wave = (mp, np),
// computing m-tiles {mp*2, mp*2+1} x n-tiles {np*2, np*2+1}.
template<int CIN, bool PADOUT, bool BN>
__global__ __launch_bounds__(256, 2) void conv3x3_tiled(
    const __hip_bfloat16* __restrict__ xp, const __hip_bfloat16* __restrict__ wb,
    const float* __restrict__ bias, const float* __restrict__ gamma,
    const float* __restrict__ beta, const float* __restrict__ mean,
    const float* __restrict__ var, __hip_bfloat16* __restrict__ outp)
{
    constexpr int KC = CIN / 32;
    constexpr int NC8 = CIN / 8;        // 16B chunks per pixel (16 or 8, pow2)
    constexpr int CINP = CIN + 4;       // +8B pixel pad -> A-read conflicts ~4-way
    __shared__ short xs[3 * 66 * CINP];
    const int blk = blockIdx.x, h = blk & 63, n = blk >> 6;
    const int tid = threadIdx.x;
    const int lane = tid & 63, wave = tid >> 6;
    const int m = lane & 15, q = lane >> 4;
    const int mp = wave & 1, np = wave >> 1;

    // stage rows h..h+2 (padded coords) = full halo; global run is contiguous:
    // flat short offset = idx*8. LDS adds per-pixel pad only.
    const short* xg = (const short*)xp + ((n * 66 + h) * 66) * CIN;
    for (int idx = tid; idx < 3 * 66 * NC8; idx += 256) {
        int p = idx / NC8;             // pow2 -> shift
        int c8 = idx & (NC8 - 1);
        short8 v = *(const short8*)(xg + idx * 8);
        *(short8*)&xs[p * CINP + c8 * 8] = v;
    }
    __syncthreads();

    f32x4 acc00 = {0.f, 0.f, 0.f, 0.f}, acc01 = {0.f, 0.f, 0.f, 0.f};
    f32x4 acc10 = {0.f, 0.f, 0.f, 0.f}, acc11 = {0.f, 0.f, 0.f, 0.f};
    const short* wgb = (const short*)wb + lane * 8;
    const int arow = mp * 32 + m;

    #pragma unroll
    for (int kh = 0; kh < 3; ++kh) {
        #pragma unroll
        for (int kw = 0; kw < 3; ++kw) {
            #pragma unroll
            for (int kc = 0; kc < KC; ++kc) {
                const short* ap = &xs[(kh * 66 + arow + kw) * CINP + kc * 32 + q * 8];
                short8 a0 = *(const short8*)ap;
                short8 a1 = *(const short8*)(ap + 16 * CINP);
                const int tap = kh * 3 + kw;
                const short* bp = wgb + (((tap * KC + kc) * 4 + np * 2) << 9);
                short8 b0 = *(const short8*)bp;
                short8 b1 = *(const short8*)(bp + 512);
                acc00 = __builtin_amdgcn_mfma_f32_16x16x32_bf16(a0, b0, acc00, 0, 0, 0);
                acc01 = __builtin_amdgcn_mfma_f32_16x16x32_bf16(a0, b1, acc01, 0, 0, 0);
                acc10 = __builtin_amdgcn_mfma_f32_16x16x32_bf16(a1, b0, acc10, 0, 0, 0);
                acc11 = __builtin_amdgcn_mfma_f32_16x16x32_bf16(a1, b1, acc11, 0, 0, 0);
            }
        }
    }

    // epilogue: C/D col(m)=co-in-tile, row(q*4+r)=px-in-tile
    float scv[2], shv[2];
    #pragma unroll
    for (int j = 0; j < 2; ++j) {
        const int c = np * 32 + j * 16 + m;
        if constexpr (BN) {
            float inv = rsqrtf(var[c] + 1e-5f);
            scv[j] = gamma[c] * inv;
            shv[j] = (bias[c] - mean[c]) * scv[j] + beta[c];
        } else {
            scv[j] = 1.f;
            shv[j] = bias[c];
        }
    }
    const f32x4* accs[2][2] = {{&acc00, &acc01}, {&acc10, &acc11}};
    #pragma unroll
    for (int i = 0; i < 2; ++i) {
        #pragma unroll
        for (int j = 0; j < 2; ++j) {
            const int c = np * 32 + j * 16 + m;
            const f32x4 a = *accs[i][j];
            #pragma unroll
            for (int r = 0; r < 4; ++r) {
                const int px = mp * 32 + i * 16 + q * 4 + r;
                float ov = fmaxf(fmaf(a[r], scv[j], shv[j]), 0.f);
                if constexpr (PADOUT)
                    outp[(((n * 66 + h + 1) * 66) + px + 1) * 64 + c] = __float2bfloat16(ov);
                else
                    outp[((n * 64 + h) * 64 + px) * 64 + c] = __float2bfloat16(ov);
            }
        }
    }
}

// ---------------- predictor: 2 MFMA GEMMs (64px x 112 x K64) + sigmoid-gate softmax ----------------
__global__ __launch_bounds__(256) void predictor_mfma(
    const __hip_bfloat16* __restrict__ cbf, const __hip_bfloat16* __restrict__ g1bf,
    const __hip_bfloat16* __restrict__ wkpt, const __hip_bfloat16* __restrict__ wg2t,
    const float* __restrict__ bkp, const float* __restrict__ bg2,
    float* __restrict__ ker)
{
    __shared__ float kers[64 * 117];
    __shared__ float gates[64 * 117];
    __shared__ float redm[256], reds[256];
    const int blk = blockIdx.x, n = blk >> 6, h = blk & 63;
    const int tid = threadIdx.x;
    const int lane = tid & 63, wave = tid >> 6;
    const int m = lane & 15, q = lane >> 4;
    const int sel = wave >> 1;
    const int half = wave & 1;
    const int nt0 = half ? 4 : 0, ntc = half ? 3 : 4;

    const short* A = sel ? (const short*)g1bf + ((n * 64 + h) * 64) * 64
                         : (const short*)cbf + (((n * 66 + h + 1) * 66) + 1) * 64;
    const short* B = sel ? (const short*)wg2t : (const short*)wkpt;

    f32x4 acc[4][4];
    #pragma unroll
    for (int a = 0; a < 4; ++a)
        #pragma unroll
        for (int b = 0; b < 4; ++b) acc[a][b] = (f32x4){0.f, 0.f, 0.f, 0.f};

    #pragma unroll
    for (int ks = 0; ks < 2; ++ks) {
        short8 af[4];
        #pragma unroll
        for (int mt = 0; mt < 4; ++mt)
            af[mt] = *(const short8*)(A + (mt * 16 + m) * 64 + ks * 32 + q * 8);
        #pragma unroll
        for (int nt = 0; nt < 4; ++nt) {
            if (nt >= ntc) break;
            short8 bf8 = *(const short8*)(B + ((nt0 + nt) * 16 + m) * 64 + ks * 32 + q * 8);
            #pragma unroll
            for (int mt = 0; mt < 4; ++mt)
                acc[mt][nt] = __builtin_amdgcn_mfma_f32_16x16x32_bf16(af[mt], bf8, acc[mt][nt], 0, 0, 0);
        }
    }

    float* dst = sel ? gates : kers;
    #pragma unroll
    for (int mt = 0; mt < 4; ++mt) {
        #pragma unroll
        for (int nt = 0; nt < 4; ++nt) {
            if (nt >= ntc) break;
            const int co = (nt0 + nt) * 16 + m;
            if (co < 100) {
                #pragma unroll
                for (int r = 0; r < 4; ++r)
                    dst[(mt * 16 + q * 4 + r) * 117 + co] = acc[mt][nt][r];
            }
        }
    }
    __syncthreads();

    const int w = tid & 63, qg = tid >> 6;
    float p[25], mx = -1e30f;
    #pragma unroll
    for (int j = 0; j < 25; ++j) {
        const int qq = qg * 25 + j;
        float ka = kers[w * 117 + qq] + bkp[qq];
        float ga = gates[w * 117 + qq] + bg2[qq];
        p[j] = ka * (1.f / (1.f + __expf(-ga)));
        mx = fmaxf(mx, p[j]);
    }
    redm[tid] = mx;
    __syncthreads();
    mx = fmaxf(fmaxf(redm[w], redm[64 + w]), fmaxf(redm[128 + w], redm[192 + w]));
    float ssum = 0.f;
    #pragma unroll
    for (int j = 0; j < 25; ++j) { p[j] = __expf(p[j] - mx); ssum += p[j]; }
    reds[tid] = ssum;
    __syncthreads();
    ssum = reds[w] + reds[64 + w] + reds[128 + w] + reds[192 + w];
    const float r = 1.f / ssum;

    #pragma unroll
    for (int j = 0; j < 25; ++j) {
        const int qq = qg * 25 + j;
        ker[((n * 100 + qq) * 64 + h) * 64 + w] = p[j] * r;
    }
}

// ---------------- content-aware reassembly + pixel shuffle ----------------
__global__ __launch_bounds__(256) void reassembly_k(
    const float* __restrict__ x, const float* __restrict__ ker,
    float* __restrict__ out)
{
    constexpr int CT = 16;
    __shared__ float xls[CT][5][68];
    const int blk = blockIdx.x;
    const int cb = blk & 7, h = (blk >> 3) & 63, n = blk >> 9;
    const int c0 = cb * CT;
    const int tid = threadIdx.x;
    const int w = tid & 63, cg = tid >> 6;

    for (int idx = tid; idx < CT * 5 * 16; idx += 256) {
        int c = idx / 80, r2 = idx % 80;
        int rr = r2 / 16, c4 = r2 % 16;
        int sr = min(max(h - 2 + rr, 0), 63);
        float4 v = *(const float4*)&x[((n * 128 + c0 + c) * 64 + sr) * 64 + c4 * 4];
        *(float2*)&xls[c][rr][2 + c4 * 4] = make_float2(v.x, v.y);
        *(float2*)&xls[c][rr][4 + c4 * 4] = make_float2(v.z, v.w);
    }
    if (tid < CT * 5) {
        int c = tid / 5, rr = tid % 5;
        int sr = min(max(h - 2 + rr, 0), 63);
        float xl = x[((n * 128 + c0 + c) * 64 + sr) * 64 + 0];
        float xr = x[((n * 128 + c0 + c) * 64 + sr) * 64 + 63];
        xls[c][rr][0] = xl; xls[c][rr][1] = xl;
        xls[c][rr][66] = xr; xls[c][rr][67] = xr;
    }
    __syncthreads();

    const float* kbase = &ker[(n * 100 * 4096) + h * 64 + w];
    float4 acc[4] = {{0.f, 0.f, 0.f, 0.f}, {0.f, 0.f, 0.f, 0.f},
                     {0.f, 0.f, 0.f, 0.f}, {0.f, 0.f, 0.f, 0.f}};
    #pragma unroll
    for (int i = 0; i < 5; ++i) {
        #pragma unroll
        for (int j = 0; j < 5; ++j) {
            const int q0 = (i * 5 + j) * 4;
            const float k0 = kbase[(q0 + 0) * 4096];
            const float k1 = kbase[(q0 + 1) * 4096];
            const float k2 = kbase[(q0 + 2) * 4096];
            const float k3 = kbase[(q0 + 3) * 4096];
            #pragma unroll
            for (int cc = 0; cc < 4; ++cc) {
                const float xv = xls[cg * 4 + cc][i][w + j];
                acc[cc].x = fmaf(xv, k0, acc[cc].x);
                acc[cc].y = fmaf(xv, k1, acc[cc].y);
                acc[cc].z = fmaf(xv, k2, acc[cc].z);
                acc[cc].w = fmaf(xv, k3, acc[cc].w);
            }
        }
    }
    #pragma unroll
    for (int cc = 0; cc < 4; ++cc) {
        const int c = c0 + cg * 4 + cc;
        *(float2*)&out[((n * 128 + c) * 128 + 2 * h + 0) * 128 + 2 * w] =
            make_float2(acc[cc].x, acc[cc].y);
        *(float2*)&out[((n * 128 + c) * 128 + 2 * h + 1) * 128 + 2 * w] =
            make_float2(acc[cc].z, acc[cc].w);
    }
}

extern "C" void kernel_launch(void* const* d_in, const int* in_sizes, int n_in,
                              void* d_out, int out_size, void* d_ws, size_t ws_size,
                              hipStream_t stream) {
    const float* x     = (const float*)d_in[0];
    const float* w_enc = (const float*)d_in[1];
    const float* b_enc = (const float*)d_in[2];
    const float* gamma = (const float*)d_in[3];
    const float* beta  = (const float*)d_in[4];
    const float* mean  = (const float*)d_in[5];
    const float* var   = (const float*)d_in[6];
    const float* w_kp  = (const float*)d_in[7];
    const float* b_kp  = (const float*)d_in[8];
    const float* w_g1  = (const float*)d_in[9];
    const float* b_g1  = (const float*)d_in[10];
    const float* w_g2  = (const float*)d_in[11];
    const float* b_g2  = (const float*)d_in[12];
    float* out = (float*)d_out;

    // ws carve
    float* ker = (float*)d_ws;                               // (N,100,64,64) f32
    __hip_bfloat16* g1bf = (__hip_bfloat16*)(ker + 3276800); // (N,64,64,64) bf16
    __hip_bfloat16* xb   = g1bf + 2097152;                   // (N,66,66,128) bf16
    __hip_bfloat16* cbf  = xb + 4460544;                     // (N,66,66,64) bf16
    __hip_bfloat16* wtt  = cbf + 2230272;                    // conv1 B-frags (73728)
    __hip_bfloat16* wgt  = wtt + 73728;                      // conv2 B-frags (36864)
    __hip_bfloat16* wkpt = wgt + 36864;                      // [112][64] bf16
    __hip_bfloat16* wg2t = wkpt + 7168;                      // [112][64] bf16

    // zero xb+cbf borders (contiguous: 6,690,816 shorts = 836,352 short8)
    zerofill8<<<3267, 256, 0, stream>>>((short*)xb, 836352);
    x_to_bf_pad<<<512, 256, 0, stream>>>(x, xb);
    w_frag<4><<<288, 256, 0, stream>>>(w_enc, wtt, 73728);
    w_frag<2><<<144, 256, 0, stream>>>(w_g1, wgt, 36864);
    wpred_to_bf<<<28, 256, 0, stream>>>(w_kp, w_g2, wkpt, wg2t);

    conv3x3_tiled<128, true, true><<<512, 256, 0, stream>>>(
        xb, wtt, b_enc, gamma, beta, mean, var, cbf);
    conv3x3_tiled<64, false, false><<<512, 256, 0, stream>>>(
        cbf, wgt, b_g1, nullptr, nullptr, nullptr, nullptr, g1bf);

    predictor_mfma<<<512, 256, 0, stream>>>(cbf, g1bf, wkpt, wg2t, b_kp, b_g2, ker);
    reassembly_k<<<4096, 256, 0, stream>>>(x, ker, out);
}

// Round 7
// 180.271 us; speedup vs baseline: 1.3097x; 1.0349x over previous
//
#include <hip/hip_runtime.h>
#include <hip/hip_bf16.h>

// CARAFE-style SAU. Round 6b (fix bf16 bit-cast):
//  - border-only zeroing (was 13.4 MB full-buffer fill)
//  - conv2 + predictor fused: g1relu via LDS, content A-frags reused from conv2's
//    own staging; softmax fully in registers (shfl_xor over the 16 m-lanes)
//  - single merged weight-prep kernel; 6 dispatches total
// N=8, Cin=128, H=W=64, Cmid=64, NK=100, K=5, S=2.

typedef __attribute__((ext_vector_type(8))) short short8;
typedef __attribute__((ext_vector_type(4))) float f32x4;

static __device__ __forceinline__ short bf16_bits(float v) {
    __hip_bfloat16 h = __float2bfloat16(v);
    return __builtin_bit_cast(short, h);
}

// ---------------- border-only zero for xb (N,66,66,128) and cbf (N,66,66,64) ----------------
// 260 border pixels per n-image: rows 0,65 (66 each) + cols 0,65 of rows 1..64 (64 each).
__global__ void zero_borders(short* __restrict__ xb, short* __restrict__ cbf) {
    const int i = blockIdx.x * 256 + threadIdx.x;  // grid 195*256 = 49920 exact
    short* base;
    int c8n, r;
    if (i < 33280) { base = xb; c8n = 16; r = i; }          // 8n*260*16
    else           { base = cbf; c8n = 8; r = i - 33280; }  // 8n*260*8
    const int c8 = r % c8n;
    const int t = r / c8n;          // n*260 + p
    const int n = t / 260, p = t % 260;
    int row, col;
    if (p < 66)       { row = 0;        col = p; }
    else if (p < 132) { row = 65;       col = p - 66; }
    else if (p < 196) { row = p - 131;  col = 0; }    // rows 1..64
    else              { row = p - 195;  col = 65; }
    ((short8*)base)[((n * 66 + row) * 66 + col) * c8n + c8] =
        (short8){0, 0, 0, 0, 0, 0, 0, 0};
}

// ---------------- prep: x (N,128,64,64) f32 -> xb (N,66,66,128) bf16 (interior) ----------------
__global__ __launch_bounds__(256) void x_to_bf_pad(const float* __restrict__ x,
                                                   __hip_bfloat16* __restrict__ xb) {
    __shared__ float ls[128 * 65];
    const int blk = blockIdx.x, n = blk >> 6, h = blk & 63;
    const int tid = threadIdx.x;
    for (int idx = tid; idx < 8192; idx += 256) {
        int ci = idx >> 6, w = idx & 63;
        ls[ci * 65 + w] = x[((n * 128 + ci) * 64 + h) * 64 + w];
    }
    __syncthreads();
    for (int idx = tid; idx < 8192; idx += 256) {
        int w = idx >> 7, ci = idx & 127;
        xb[(((n * 66 + h + 1) * 66) + w + 1) * 128 + ci] = __float2bfloat16(ls[ci * 65 + w]);
    }
}

// ---------------- merged weight prep ----------------
// [0,73728):            conv1 B-frags (KC=4, CIN=128) from w_enc
// [73728,110592):       conv2 B-frags (KC=2, CIN=64)  from w_g1
// [110592,117760):      predictor weights [112][64] bf16 (both kp and g2)
__global__ void w_all(const float* __restrict__ w_enc, const float* __restrict__ w_g1,
                      const float* __restrict__ w_kp, const float* __restrict__ w_g2,
                      __hip_bfloat16* __restrict__ wtt, __hip_bfloat16* __restrict__ wgt,
                      __hip_bfloat16* __restrict__ wkpt, __hip_bfloat16* __restrict__ wg2t) {
    int idx = blockIdx.x * 256 + threadIdx.x;
    if (idx < 73728) {
        int j = idx & 7, lane = (idx >> 3) & 63, nt = (idx >> 9) & 3, rest = idx >> 11;
        int kc = rest & 3, tap = rest >> 2;
        int co = nt * 16 + (lane & 15), ci = kc * 32 + (lane >> 4) * 8 + j;
        wtt[idx] = __float2bfloat16(w_enc[(co * 128 + ci) * 9 + tap]);
    } else if (idx < 110592) {
        int local = idx - 73728;
        int j = local & 7, lane = (local >> 3) & 63, nt = (local >> 9) & 3, rest = local >> 11;
        int kc = rest & 1, tap = rest >> 1;
        int co = nt * 16 + (lane & 15), ci = kc * 32 + (lane >> 4) * 8 + j;
        wgt[local] = __float2bfloat16(w_g1[(co * 64 + ci) * 9 + tap]);
    } else if (idx < 117760) {
        int local = idx - 110592;
        int co = local >> 6, ci = local & 63;
        float a = co < 100 ? w_kp[co * 64 + ci] : 0.f;
        float b = co < 100 ? w_g2[co * 64 + ci] : 0.f;
        wkpt[local] = __float2bfloat16(a);
        wg2t[local] = __float2bfloat16(b);
    }
}

// ---------------- conv1: single-barrier LDS-staged MFMA ----------------
__global__ __launch_bounds__(256, 2) void conv1_tiled(
    const __hip_bfloat16* __restrict__ xp, const __hip_bfloat16* __restrict__ wb,
    const float* __restrict__ bias, const float* __restrict__ gamma,
    const float* __restrict__ beta, const float* __restrict__ mean,
    const float* __restrict__ var, __hip_bfloat16* __restrict__ outp)
{
    constexpr int CIN = 128, KC = 4, NC8 = 16, CINP = 132;
    __shared__ short xs[3 * 66 * CINP];
    const int blk = blockIdx.x, h = blk & 63, n = blk >> 6;
    const int tid = threadIdx.x;
    const int lane = tid & 63, wave = tid >> 6;
    const int m = lane & 15, q = lane >> 4;
    const int mp = wave & 1, np = wave >> 1;

    const short* xg = (const short*)xp + ((n * 66 + h) * 66) * CIN;
    for (int idx = tid; idx < 3 * 66 * NC8; idx += 256) {
        int p = idx >> 4;
        int c8 = idx & 15;
        short8 v = *(const short8*)(xg + idx * 8);
        *(short8*)&xs[p * CINP + c8 * 8] = v;
    }
    __syncthreads();

    f32x4 acc00 = {0.f, 0.f, 0.f, 0.f}, acc01 = {0.f, 0.f, 0.f, 0.f};
    f32x4 acc10 = {0.f, 0.f, 0.f, 0.f}, acc11 = {0.f, 0.f, 0.f, 0.f};
    const short* wgb = (const short*)wb + lane * 8;
    const int arow = mp * 32 + m;

    #pragma unroll
    for (int kh = 0; kh < 3; ++kh) {
        #pragma unroll
        for (int kw = 0; kw < 3; ++kw) {
            #pragma unroll
            for (int kc = 0; kc < KC; ++kc) {
                const short* ap = &xs[(kh * 66 + arow + kw) * CINP + kc * 32 + q * 8];
                short8 a0 = *(const short8*)ap;
                short8 a1 = *(const short8*)(ap + 16 * CINP);
                const int tap = kh * 3 + kw;
                const short* bp = wgb + (((tap * KC + kc) * 4 + np * 2) << 9);
                short8 b0 = *(const short8*)bp;
                short8 b1 = *(const short8*)(bp + 512);
                acc00 = __builtin_amdgcn_mfma_f32_16x16x32_bf16(a0, b0, acc00, 0, 0, 0);
                acc01 = __builtin_amdgcn_mfma_f32_16x16x32_bf16(a0, b1, acc01, 0, 0, 0);
                acc10 = __builtin_amdgcn_mfma_f32_16x16x32_bf16(a1, b0, acc10, 0, 0, 0);
                acc11 = __builtin_amdgcn_mfma_f32_16x16x32_bf16(a1, b1, acc11, 0, 0, 0);
            }
        }
    }

    float scv[2], shv[2];
    #pragma unroll
    for (int j = 0; j < 2; ++j) {
        const int c = np * 32 + j * 16 + m;
        float inv = rsqrtf(var[c] + 1e-5f);
        scv[j] = gamma[c] * inv;
        shv[j] = (bias[c] - mean[c]) * scv[j] + beta[c];
    }
    const f32x4* accs[2][2] = {{&acc00, &acc01}, {&acc10, &acc11}};
    #pragma unroll
    for (int i = 0; i < 2; ++i) {
        #pragma unroll
        for (int j = 0; j < 2; ++j) {
            const int c = np * 32 + j * 16 + m;
            const f32x4 a = *accs[i][j];
            #pragma unroll
            for (int r = 0; r < 4; ++r) {
                const int px = mp * 32 + i * 16 + q * 4 + r;
                float ov = fmaxf(fmaf(a[r], scv[j], shv[j]), 0.f);
                outp[(((n * 66 + h + 1) * 66) + px + 1) * 64 + c] = __float2bfloat16(ov);
            }
        }
    }
}

// ---------------- fused conv2 + predictor + softmax ----------------
// cbf: (N,66,66,64) padded content bf16; wgt: conv2 B-frags; wkpt/wg2t: [112][64] bf16.
// Block (n,h). Phase A: conv2 3x3 + bias + ReLU -> g1s in LDS.
// Phase B: wave = m-tile; both GEMMs (kp from xs, gate from g1s) x 7 n-tiles in regs;
// p = ka*sigmoid(ga); softmax over 100 via per-lane partials + shfl_xor(1,2,4,8);
// planar store ker (N,100,64,64).
__global__ __launch_bounds__(256, 2) void conv2_predictor(
    const __hip_bfloat16* __restrict__ cbf, const __hip_bfloat16* __restrict__ wb,
    const float* __restrict__ b_g1,
    const __hip_bfloat16* __restrict__ wkpt, const __hip_bfloat16* __restrict__ wg2t,
    const float* __restrict__ bkp, const float* __restrict__ bg2,
    float* __restrict__ ker)
{
    constexpr int CIN = 64, KC = 2, NC8 = 8, CINP = 68;
    __shared__ short xs[3 * 66 * CINP];   // 26.9 KB
    __shared__ short g1s[64 * 68];        // 8.7 KB, [px][co] stride 68
    const int blk = blockIdx.x, h = blk & 63, n = blk >> 6;
    const int tid = threadIdx.x;
    const int lane = tid & 63, wave = tid >> 6;
    const int m = lane & 15, q = lane >> 4;

    // stage content rows h..h+2 (padded coords)
    const short* xg = (const short*)cbf + ((n * 66 + h) * 66) * CIN;
    for (int idx = tid; idx < 3 * 66 * NC8; idx += 256) {
        int p = idx >> 3;
        int c8 = idx & 7;
        short8 v = *(const short8*)(xg + idx * 8);
        *(short8*)&xs[p * CINP + c8 * 8] = v;
    }
    __syncthreads();

    // ---- phase A: conv2 ----
    {
        const int mp = wave & 1, np = wave >> 1;
        f32x4 acc00 = {0.f, 0.f, 0.f, 0.f}, acc01 = {0.f, 0.f, 0.f, 0.f};
        f32x4 acc10 = {0.f, 0.f, 0.f, 0.f}, acc11 = {0.f, 0.f, 0.f, 0.f};
        const short* wgb = (const short*)wb + lane * 8;
        const int arow = mp * 32 + m;
        #pragma unroll
        for (int kh = 0; kh < 3; ++kh) {
            #pragma unroll
            for (int kw = 0; kw < 3; ++kw) {
                #pragma unroll
                for (int kc = 0; kc < KC; ++kc) {
                    const short* ap = &xs[(kh * 66 + arow + kw) * CINP + kc * 32 + q * 8];
                    short8 a0 = *(const short8*)ap;
                    short8 a1 = *(const short8*)(ap + 16 * CINP);
                    const int tap = kh * 3 + kw;
                    const short* bp = wgb + (((tap * KC + kc) * 4 + np * 2) << 9);
                    short8 b0 = *(const short8*)bp;
                    short8 b1 = *(const short8*)(bp + 512);
                    acc00 = __builtin_amdgcn_mfma_f32_16x16x32_bf16(a0, b0, acc00, 0, 0, 0);
                    acc01 = __builtin_amdgcn_mfma_f32_16x16x32_bf16(a0, b1, acc01, 0, 0, 0);
                    acc10 = __builtin_amdgcn_mfma_f32_16x16x32_bf16(a1, b0, acc10, 0, 0, 0);
                    acc11 = __builtin_amdgcn_mfma_f32_16x16x32_bf16(a1, b1, acc11, 0, 0, 0);
                }
            }
        }
        const f32x4* accs[2][2] = {{&acc00, &acc01}, {&acc10, &acc11}};
        #pragma unroll
        for (int i = 0; i < 2; ++i) {
            #pragma unroll
            for (int j = 0; j < 2; ++j) {
                const int c = np * 32 + j * 16 + m;
                const float bb = b_g1[c];
                const f32x4 a = *accs[i][j];
                #pragma unroll
                for (int r = 0; r < 4; ++r) {
                    const int px = mp * 32 + i * 16 + q * 4 + r;
                    float ov = fmaxf(a[r] + bb, 0.f);
                    g1s[px * 68 + c] = bf16_bits(ov);
                }
            }
        }
    }
    __syncthreads();

    // ---- phase B: predictor GEMMs, wave = m-tile ----
    const int mt = wave;
    const short* aK = &xs[(66 + 1 + mt * 16 + m) * CINP];   // content row h, px col
    const short* aG = &g1s[(mt * 16 + m) * 68];
    const short* BK = (const short*)wkpt + m * 64;
    const short* BG = (const short*)wg2t + m * 64;

    f32x4 kacc[7], gacc[7];
    #pragma unroll
    for (int nt = 0; nt < 7; ++nt) {
        kacc[nt] = (f32x4){0.f, 0.f, 0.f, 0.f};
        gacc[nt] = (f32x4){0.f, 0.f, 0.f, 0.f};
    }
    #pragma unroll
    for (int ks = 0; ks < 2; ++ks) {
        short8 ak = *(const short8*)(aK + ks * 32 + q * 8);
        short8 ag = *(const short8*)(aG + ks * 32 + q * 8);
        #pragma unroll
        for (int nt = 0; nt < 7; ++nt) {
            short8 bk = *(const short8*)(BK + nt * 1024 + ks * 32 + q * 8);
            short8 bg = *(const short8*)(BG + nt * 1024 + ks * 32 + q * 8);
            kacc[nt] = __builtin_amdgcn_mfma_f32_16x16x32_bf16(ak, bk, kacc[nt], 0, 0, 0);
            gacc[nt] = __builtin_amdgcn_mfma_f32_16x16x32_bf16(ag, bg, gacc[nt], 0, 0, 0);
        }
    }

    // p = ka*sigmoid(ga) per lane; lane holds (px = mt*16+q*4+r, co = nt*16+m)
    float p[7][4];
    float mxr[4] = {-1e30f, -1e30f, -1e30f, -1e30f};
    #pragma unroll
    for (int nt = 0; nt < 7; ++nt) {
        const int co = nt * 16 + m;
        const bool valid = co < 100;
        const float bk = valid ? bkp[co] : 0.f;
        const float bg = valid ? bg2[co] : 0.f;
        #pragma unroll
        for (int r = 0; r < 4; ++r) {
            float ka = kacc[nt][r] + bk;
            float ga = gacc[nt][r] + bg;
            float v = valid ? ka * (1.f / (1.f + __expf(-ga))) : -1e30f;
            p[nt][r] = v;
            mxr[r] = fmaxf(mxr[r], v);
        }
    }
    // cross-lane max over the 16 m-lanes (xor 1,2,4,8 stays in the q-group)
    #pragma unroll
    for (int msk = 1; msk <= 8; msk <<= 1) {
        #pragma unroll
        for (int r = 0; r < 4; ++r)
            mxr[r] = fmaxf(mxr[r], __shfl_xor(mxr[r], msk, 64));
    }
    float sr[4] = {0.f, 0.f, 0.f, 0.f};
    #pragma unroll
    for (int nt = 0; nt < 7; ++nt) {
        #pragma unroll
        for (int r = 0; r < 4; ++r) {
            p[nt][r] = __expf(p[nt][r] - mxr[r]);   // invalid -> exp(-huge) = 0
            sr[r] += p[nt][r];
        }
    }
    #pragma unroll
    for (int msk = 1; msk <= 8; msk <<= 1) {
        #pragma unroll
        for (int r = 0; r < 4; ++r)
            sr[r] += __shfl_xor(sr[r], msk, 64);
    }
    float rinv[4];
    #pragma unroll
    for (int r = 0; r < 4; ++r) rinv[r] = 1.f / sr[r];

    // planar store ker[n][co][h][w], w = mt*16 + q*4 + r
    #pragma unroll
    for (int nt = 0; nt < 7; ++nt) {
        const int co = nt * 16 + m;
        if (co < 100) {
            #pragma unroll
            for (int r = 0; r < 4; ++r) {
                const int w = mt * 16 + q * 4 + r;
                ker[((n * 100 + co) * 64 + h) * 64 + w] = p[nt][r] * rinv[r];
            }
        }
    }
}

// ---------------- content-aware reassembly + pixel shuffle ----------------
__global__ __launch_bounds__(256) void reassembly_k(
    const float* __restrict__ x, const float* __restrict__ ker,
    float* __restrict__ out)
{
    constexpr int CT = 16;
    __shared__ float xls[CT][5][68];
    const int blk = blockIdx.x;
    const int cb = blk & 7, h = (blk >> 3) & 63, n = blk >> 9;
    const int c0 = cb * CT;
    const int tid = threadIdx.x;
    const int w = tid & 63, cg = tid >> 6;

    for (int idx = tid; idx < CT * 5 * 16; idx += 256) {
        int c = idx / 80, r2 = idx % 80;
        int rr = r2 / 16, c4 = r2 % 16;
        int sr = min(max(h - 2 + rr, 0), 63);
        float4 v = *(const float4*)&x[((n * 128 + c0 + c) * 64 + sr) * 64 + c4 * 4];
        *(float2*)&xls[c][rr][2 + c4 * 4] = make_float2(v.x, v.y);
        *(float2*)&xls[c][rr][4 + c4 * 4] = make_float2(v.z, v.w);
    }
    if (tid < CT * 5) {
        int c = tid / 5, rr = tid % 5;
        int sr = min(max(h - 2 + rr, 0), 63);
        float xl = x[((n * 128 + c0 + c) * 64 + sr) * 64 + 0];
        float xr = x[((n * 128 + c0 + c) * 64 + sr) * 64 + 63];
        xls[c][rr][0] = xl; xls[c][rr][1] = xl;
        xls[c][rr][66] = xr; xls[c][rr][67] = xr;
    }
    __syncthreads();

    const float* kbase = &ker[(n * 100 * 4096) + h * 64 + w];
    float4 acc[4] = {{0.f, 0.f, 0.f, 0.f}, {0.f, 0.f, 0.f, 0.f},
                     {0.f, 0.f, 0.f, 0.f}, {0.f, 0.f, 0.f, 0.f}};
    #pragma unroll
    for (int i = 0; i < 5; ++i) {
        #pragma unroll
        for (int j = 0; j < 5; ++j) {
            const int q0 = (i * 5 + j) * 4;
            const float k0 = kbase[(q0 + 0) * 4096];
            const float k1 = kbase[(q0 + 1) * 4096];
            const float k2 = kbase[(q0 + 2) * 4096];
            const float k3 = kbase[(q0 + 3) * 4096];
            #pragma unroll
            for (int cc = 0; cc < 4; ++cc) {
                const float xv = xls[cg * 4 + cc][i][w + j];
                acc[cc].x = fmaf(xv, k0, acc[cc].x);
                acc[cc].y = fmaf(xv, k1, acc[cc].y);
                acc[cc].z = fmaf(xv, k2, acc[cc].z);
                acc[cc].w = fmaf(xv, k3, acc[cc].w);
            }
        }
    }
    #pragma unroll
    for (int cc = 0; cc < 4; ++cc) {
        const int c = c0 + cg * 4 + cc;
        *(float2*)&out[((n * 128 + c) * 128 + 2 * h + 0) * 128 + 2 * w] =
            make_float2(acc[cc].x, acc[cc].y);
        *(float2*)&out[((n * 128 + c) * 128 + 2 * h + 1) * 128 + 2 * w] =
            make_float2(acc[cc].z, acc[cc].w);
    }
}

extern "C" void kernel_launch(void* const* d_in, const int* in_sizes, int n_in,
                              void* d_out, int out_size, void* d_ws, size_t ws_size,
                              hipStream_t stream) {
    const float* x     = (const float*)d_in[0];
    const float* w_enc = (const float*)d_in[1];
    const float* b_enc = (const float*)d_in[2];
    const float* gamma = (const float*)d_in[3];
    const float* beta  = (const float*)d_in[4];
    const float* mean  = (const float*)d_in[5];
    const float* var   = (const float*)d_in[6];
    const float* w_kp  = (const float*)d_in[7];
    const float* b_kp  = (const float*)d_in[8];
    const float* w_g1  = (const float*)d_in[9];
    const float* b_g1  = (const float*)d_in[10];
    const float* w_g2  = (const float*)d_in[11];
    const float* b_g2  = (const float*)d_in[12];
    float* out = (float*)d_out;

    // ws carve
    float* ker = (float*)d_ws;                               // (N,100,64,64) f32
    __hip_bfloat16* xb   = (__hip_bfloat16*)(ker + 3276800); // (N,66,66,128) bf16
    __hip_bfloat16* cbf  = xb + 4460544;                     // (N,66,66,64) bf16
    __hip_bfloat16* wtt  = cbf + 2230272;                    // conv1 B-frags (73728)
    __hip_bfloat16* wgt  = wtt + 73728;                      // conv2 B-frags (36864)
    __hip_bfloat16* wkpt = wgt + 36864;                      // [112][64] bf16
    __hip_bfloat16* wg2t = wkpt + 7168;                      // [112][64] bf16

    zero_borders<<<195, 256, 0, stream>>>((short*)xb, (short*)cbf);
    x_to_bf_pad<<<512, 256, 0, stream>>>(x, xb);
    w_all<<<460, 256, 0, stream>>>(w_enc, w_g1, w_kp, w_g2, wtt, wgt, wkpt, wg2t);

    conv1_tiled<<<512, 256, 0, stream>>>(
        xb, wtt, b_enc, gamma, beta, mean, var, cbf);
    conv2_predictor<<<512, 256, 0, stream>>>(
        cbf, wgt, b_g1, wkpt, wg2t, b_kp, b_g2, ker);
    reassembly_k<<<4096, 256, 0, stream>>>(x, ker, out);
}